// Round 6
// baseline (63.533 us; speedup 1.0000x reference)
//
#include <hip/hip_runtime.h>

// Shapes fixed by the reference setup_inputs():
//   x: [B=32, C=64, H=128, W=128] f32
//   offset: [B=32, 2, GH=64, GW=64] f32
//   out: [B, C, GH, GW] f32, scale = 2.0, shift read from device scalar
#define BB 32
#define CC 64
#define HH 128
#define WW 128
#define GH 64
#define GW 64
#define PLANE (HH * WW)   // 16384 floats = 64 KB
#define OUTP  (GH * GW)   // 4096
#define CPB 4             // channel-planes per block (share one b's weights)

// T14 async-stage split: issue plane loads to REGISTERS early (under the
// previous plane's compute), ds_write late. Single 64 KB LDS buffer keeps
// 2-blocks/CU occupancy possible; in-block overlap no longer depends on it.
__global__ __launch_bounds__(1024) void defem_kernel(
    const float* __restrict__ x,
    const float* __restrict__ off,
    const int* __restrict__ shift_p,
    float* __restrict__ out)
{
    __shared__ float plane[PLANE];   // 64 KB

    const int tid = threadIdx.x;
    const int blk = blockIdx.x;      // 512 blocks
    const int b   = blk >> 4;        // 16 blocks per b
    const int c0  = (blk & 15) * CPB;

    const float* __restrict__ src0 = x + (size_t)(b * CC + c0) * PLANE;
    const float* __restrict__ offb = off + (size_t)b * 2 * OUTP;
    float* __restrict__ out0 = out + (size_t)(b * CC + c0) * OUTP;

    // ---- issue plane-0 loads first so they fly during weight precompute
    float4 st[4];
    #pragma unroll
    for (int k = 0; k < 4; ++k)
        st[k] = *(const float4*)(src0 + k * 4096 + tid * 4);

    // ---- precompute sampling state (shared across all CPB channels)
    const float shift = (float)shift_p[0];
    int rA[4], rB[4];
    float u0a[4], u0b[4], u1a[4], u1b[4];

    #pragma unroll
    for (int k = 0; k < 4; ++k) {
        const int s  = k * 1024 + tid;
        const int gw = s & (GW - 1);
        const int gh = s >> 6;

        const float dy = offb[s];
        const float dx = offb[OUTP + s];

        const float y  = (float)gh * 2.0f + shift + dy;
        const float xx = (float)gw * 2.0f + shift + dx;

        const float y0f = floorf(y);
        const float x0f = floorf(xx);
        const float wy1 = y - y0f;
        const float wx1 = xx - x0f;
        const float wy0 = 1.0f - wy1;
        const float wx0 = 1.0f - wx1;
        const int y0 = (int)y0f;
        const int x0 = (int)x0f;
        const int y1 = y0 + 1;
        const int x1 = x0 + 1;

        const float vy0 = (y0 >= 0 && y0 < HH) ? 1.0f : 0.0f;
        const float vy1 = (y1 >= 0 && y1 < HH) ? 1.0f : 0.0f;
        const float vx0 = (x0 >= 0 && x0 < WW) ? 1.0f : 0.0f;
        const float vx1 = (x1 >= 0 && x1 < WW) ? 1.0f : 0.0f;

        const float w00 = wy0 * wx0 * vy0 * vx0;
        const float w01 = wy0 * wx1 * vy0 * vx1;
        const float w10 = wy1 * wx0 * vy1 * vx0;
        const float w11 = wy1 * wx1 * vy1 * vx1;

        const int yc0 = min(max(y0, 0), HH - 1);
        const int yc1 = min(max(y1, 0), HH - 1);
        // pair (xs, xs+1) always contains every valid-weighted pixel;
        // invalid halves carry zero weight. Pre-swap weights per `sel`.
        const int xs  = min(max(x0, 0), WW - 2);
        const bool sel = (x0 == xs);

        u0a[k] = sel ? w00 : w01;
        u0b[k] = sel ? w01 : w00;
        u1a[k] = sel ? w10 : w11;
        u1b[k] = sel ? w11 : w10;
        rA[k] = yc0 * WW + xs;
        rB[k] = yc1 * WW + xs;
    }

    // ---- write plane 0 to LDS (s_waitcnt on the loads lands here)
    #pragma unroll
    for (int k = 0; k < 4; ++k)
        *(float4*)(plane + k * 4096 + tid * 4) = st[k];
    __syncthreads();

    // ---- plane loop: loads for p+1 fly under compute of p
    #pragma unroll 1
    for (int p = 0; p < CPB; ++p) {
        if (p + 1 < CPB) {
            const float* __restrict__ srcn = src0 + (size_t)(p + 1) * PLANE;
            #pragma unroll
            for (int k = 0; k < 4; ++k)
                st[k] = *(const float4*)(srcn + k * 4096 + tid * 4);
        }

        float* __restrict__ ob = out0 + (size_t)p * OUTP;
        #pragma unroll
        for (int k = 0; k < 4; ++k) {
            const int s = k * 1024 + tid;
            const float a0 = plane[rA[k]];
            const float a1 = plane[rA[k] + 1];
            const float b0 = plane[rB[k]];
            const float b1 = plane[rB[k] + 1];
            ob[s] = a0 * u0a[k] + a1 * u0b[k] + b0 * u1a[k] + b1 * u1b[k];
        }

        __syncthreads();   // all reads of `plane` done before overwrite

        if (p + 1 < CPB) {
            #pragma unroll
            for (int k = 0; k < 4; ++k)
                *(float4*)(plane + k * 4096 + tid * 4) = st[k];
            __syncthreads();   // writes visible before next compute
        }
    }
}

extern "C" void kernel_launch(void* const* d_in, const int* in_sizes, int n_in,
                              void* d_out, int out_size, void* d_ws, size_t ws_size,
                              hipStream_t stream) {
    const float* x   = (const float*)d_in[0];
    const float* off = (const float*)d_in[1];
    const int* shift_p = (const int*)d_in[4];
    float* out = (float*)d_out;

    const int grid = BB * CC / CPB;   // 512 blocks, 4 planes each
    defem_kernel<<<grid, 1024, 0, stream>>>(x, off, shift_p, out);
}

// Round 7
// 32.327 us; speedup vs baseline: 1.9653x; 1.9653x over previous
//
#include <hip/hip_runtime.h>

// Shapes fixed by the reference setup_inputs():
//   x: [B=32, C=64, H=128, W=128] f32
//   offset: [B=32, 2, GH=64, GW=64] f32
//   out: [B, C, GH, GW] f32, scale = 2.0, shift read from device scalar
#define BB 32
#define CC 64
#define HH 128
#define WW 128
#define GH 64
#define GW 64
#define PLANE (HH * WW)   // 16384 floats = 64 KB
#define OUTP  (GH * GW)   // 4096
#define CPB 4             // channel-planes per block (share one b's weights)

// T14 async-stage split: issue plane loads to REGISTERS early (under the
// previous plane's compute), ds_write late. Single 64 KB LDS buffer keeps
// 2 blocks/CU; __launch_bounds__(1024, 4) sets the VGPR cap to 128 so the
// staging regs + cached weights DON'T spill to scratch (round-6 failure:
// VGPR=32, ~130 MB of scratch traffic, 2x regression).
__global__ __launch_bounds__(1024, 4) void defem_kernel(
    const float* __restrict__ x,
    const float* __restrict__ off,
    const int* __restrict__ shift_p,
    float* __restrict__ out)
{
    __shared__ float plane[PLANE];   // 64 KB

    const int tid = threadIdx.x;
    const int blk = blockIdx.x;      // 512 blocks
    const int b   = blk >> 4;        // 16 blocks per b
    const int c0  = (blk & 15) * CPB;

    const float* __restrict__ src0 = x + (size_t)(b * CC + c0) * PLANE;
    const float* __restrict__ offb = off + (size_t)b * 2 * OUTP;
    float* __restrict__ out0 = out + (size_t)(b * CC + c0) * OUTP;

    // ---- issue plane-0 loads first so they fly during weight precompute
    float4 st0 = *(const float4*)(src0 +        tid * 4);
    float4 st1 = *(const float4*)(src0 + 4096 + tid * 4);
    float4 st2 = *(const float4*)(src0 + 8192 + tid * 4);
    float4 st3 = *(const float4*)(src0 + 12288 + tid * 4);

    // ---- precompute sampling state (shared across all CPB channels)
    const float shift = (float)shift_p[0];
    int rA[4], rB[4];
    float u0a[4], u0b[4], u1a[4], u1b[4];

    #pragma unroll
    for (int k = 0; k < 4; ++k) {
        const int s  = k * 1024 + tid;
        const int gw = s & (GW - 1);
        const int gh = s >> 6;

        const float dy = offb[s];
        const float dx = offb[OUTP + s];

        const float y  = (float)gh * 2.0f + shift + dy;
        const float xx = (float)gw * 2.0f + shift + dx;

        const float y0f = floorf(y);
        const float x0f = floorf(xx);
        const float wy1 = y - y0f;
        const float wx1 = xx - x0f;
        const float wy0 = 1.0f - wy1;
        const float wx0 = 1.0f - wx1;
        const int y0 = (int)y0f;
        const int x0 = (int)x0f;
        const int y1 = y0 + 1;
        const int x1 = x0 + 1;

        const float vy0 = (y0 >= 0 && y0 < HH) ? 1.0f : 0.0f;
        const float vy1 = (y1 >= 0 && y1 < HH) ? 1.0f : 0.0f;
        const float vx0 = (x0 >= 0 && x0 < WW) ? 1.0f : 0.0f;
        const float vx1 = (x1 >= 0 && x1 < WW) ? 1.0f : 0.0f;

        const float w00 = wy0 * wx0 * vy0 * vx0;
        const float w01 = wy0 * wx1 * vy0 * vx1;
        const float w10 = wy1 * wx0 * vy1 * vx0;
        const float w11 = wy1 * wx1 * vy1 * vx1;

        const int yc0 = min(max(y0, 0), HH - 1);
        const int yc1 = min(max(y1, 0), HH - 1);
        // pair (xs, xs+1) always contains every valid-weighted pixel;
        // invalid halves carry zero weight. Pre-swap weights per `sel`.
        const int xs  = min(max(x0, 0), WW - 2);
        const bool sel = (x0 == xs);

        u0a[k] = sel ? w00 : w01;
        u0b[k] = sel ? w01 : w00;
        u1a[k] = sel ? w10 : w11;
        u1b[k] = sel ? w11 : w10;
        rA[k] = yc0 * WW + xs;
        rB[k] = yc1 * WW + xs;
    }

    // ---- write plane 0 to LDS (s_waitcnt on the loads lands here)
    *(float4*)(plane +        tid * 4) = st0;
    *(float4*)(plane + 4096 + tid * 4) = st1;
    *(float4*)(plane + 8192 + tid * 4) = st2;
    *(float4*)(plane + 12288 + tid * 4) = st3;
    __syncthreads();

    // ---- plane loop: loads for p+1 fly under compute of p
    #pragma unroll 1
    for (int p = 0; p < CPB; ++p) {
        if (p + 1 < CPB) {
            const float* __restrict__ srcn = src0 + (size_t)(p + 1) * PLANE;
            st0 = *(const float4*)(srcn +        tid * 4);
            st1 = *(const float4*)(srcn + 4096 + tid * 4);
            st2 = *(const float4*)(srcn + 8192 + tid * 4);
            st3 = *(const float4*)(srcn + 12288 + tid * 4);
        }

        float* __restrict__ ob = out0 + (size_t)p * OUTP;
        #pragma unroll
        for (int k = 0; k < 4; ++k) {
            const int s = k * 1024 + tid;
            const float a0 = plane[rA[k]];
            const float a1 = plane[rA[k] + 1];
            const float b0 = plane[rB[k]];
            const float b1 = plane[rB[k] + 1];
            ob[s] = a0 * u0a[k] + a1 * u0b[k] + b0 * u1a[k] + b1 * u1b[k];
        }

        __syncthreads();   // all reads of `plane` done before overwrite

        if (p + 1 < CPB) {
            *(float4*)(plane +        tid * 4) = st0;
            *(float4*)(plane + 4096 + tid * 4) = st1;
            *(float4*)(plane + 8192 + tid * 4) = st2;
            *(float4*)(plane + 12288 + tid * 4) = st3;
            __syncthreads();   // writes visible before next compute
        }
    }
}

extern "C" void kernel_launch(void* const* d_in, const int* in_sizes, int n_in,
                              void* d_out, int out_size, void* d_ws, size_t ws_size,
                              hipStream_t stream) {
    const float* x   = (const float*)d_in[0];
    const float* off = (const float*)d_in[1];
    const int* shift_p = (const int*)d_in[4];
    float* out = (float*)d_out;

    const int grid = BB * CC / CPB;   // 512 blocks, 4 planes each
    defem_kernel<<<grid, 1024, 0, stream>>>(x, off, shift_p, out);
}

// Round 8
// 31.063 us; speedup vs baseline: 2.0453x; 1.0407x over previous
//
#include <hip/hip_runtime.h>

// Shapes fixed by the reference setup_inputs():
//   x: [B=32, C=64, H=128, W=128] f32
//   offset: [B=32, 2, GH=64, GW=64] f32
//   out: [B, C, GH, GW] f32, scale = 2.0, shift read from device scalar
#define BB 32
#define CC 64
#define HH 128
#define WW 128
#define GH 64
#define GW 64
#define PLANE (HH * WW)   // 16384 floats = 64 KB
#define OUTP  (GH * GW)   // 4096

// R4 structure (one block per (b,c) plane; stage -> barrier -> compute)
// with global->LDS DMA staging (no VGPR round-trip, no ds_write) and a
// hard VGPR<=64 cap so 2 blocks/CU (32 waves) is guaranteed — the
// cross-block stagger is what actually covers the HBM stage latency
// (rounds 5/7 showed in-block pipelining that costs occupancy loses).
__global__ __launch_bounds__(1024, 8) void defem_kernel(
    const float* __restrict__ x,
    const float* __restrict__ off,
    const int* __restrict__ shift_p,
    float* __restrict__ out)
{
    __shared__ float plane[PLANE];   // 64 KB -> 2 blocks/CU

    const int tid = threadIdx.x;
    const int blk = blockIdx.x;      // blk = b*CC + c
    const int b   = blk >> 6;        // CC = 64

    const float* __restrict__ src  = x + (size_t)blk * PLANE;
    const float* __restrict__ offb = off + (size_t)b * 2 * OUTP;

    // ---- issue full-plane DMA first; 64 KB in flight immediately
    #pragma unroll
    for (int k = 0; k < 4; ++k) {
        const int fo = k * 4096 + tid * 4;   // float idx; 16 B per lane, linear
        __builtin_amdgcn_global_load_lds(
            (const __attribute__((address_space(1))) void*)(src + fo),
            (__attribute__((address_space(3))) void*)(plane + fo),
            16, 0, 0);
    }

    // ---- weight/index precompute hides under the DMA
    const float shift = (float)shift_p[0];
    int rA[4], rB[4];
    float u0a[4], u0b[4], u1a[4], u1b[4];

    #pragma unroll
    for (int k = 0; k < 4; ++k) {
        const int s  = k * 1024 + tid;
        const int gw = s & (GW - 1);
        const int gh = s >> 6;

        const float dy = offb[s];
        const float dx = offb[OUTP + s];

        const float y  = (float)gh * 2.0f + shift + dy;
        const float xx = (float)gw * 2.0f + shift + dx;

        const float y0f = floorf(y);
        const float x0f = floorf(xx);
        const float wy1 = y - y0f;
        const float wx1 = xx - x0f;
        const float wy0 = 1.0f - wy1;
        const float wx0 = 1.0f - wx1;
        const int y0 = (int)y0f;
        const int x0 = (int)x0f;
        const int y1 = y0 + 1;
        const int x1 = x0 + 1;

        const float vy0 = (y0 >= 0 && y0 < HH) ? 1.0f : 0.0f;
        const float vy1 = (y1 >= 0 && y1 < HH) ? 1.0f : 0.0f;
        const float vx0 = (x0 >= 0 && x0 < WW) ? 1.0f : 0.0f;
        const float vx1 = (x1 >= 0 && x1 < WW) ? 1.0f : 0.0f;

        const float w00 = wy0 * wx0 * vy0 * vx0;
        const float w01 = wy0 * wx1 * vy0 * vx1;
        const float w10 = wy1 * wx0 * vy1 * vx0;
        const float w11 = wy1 * wx1 * vy1 * vx1;

        const int yc0 = min(max(y0, 0), HH - 1);
        const int yc1 = min(max(y1, 0), HH - 1);
        // pair (xs, xs+1) always contains every valid-weighted pixel;
        // invalid halves carry zero weight. Pre-swap weights per `sel`.
        const int xs  = min(max(x0, 0), WW - 2);
        const bool sel = (x0 == xs);

        u0a[k] = sel ? w00 : w01;
        u0b[k] = sel ? w01 : w00;
        u1a[k] = sel ? w10 : w11;
        u1b[k] = sel ? w11 : w10;
        rA[k] = yc0 * WW + xs;
        rB[k] = yc1 * WW + xs;
    }

    __syncthreads();   // drains vmcnt -> plane fully staged

    float* __restrict__ obase = out + (size_t)blk * OUTP;

    #pragma unroll
    for (int k = 0; k < 4; ++k) {
        const int s = k * 1024 + tid;
        const float a0 = plane[rA[k]];
        const float a1 = plane[rA[k] + 1];
        const float b0 = plane[rB[k]];
        const float b1 = plane[rB[k] + 1];
        obase[s] = a0 * u0a[k] + a1 * u0b[k] + b0 * u1a[k] + b1 * u1b[k];
    }
}

extern "C" void kernel_launch(void* const* d_in, const int* in_sizes, int n_in,
                              void* d_out, int out_size, void* d_ws, size_t ws_size,
                              hipStream_t stream) {
    const float* x   = (const float*)d_in[0];
    const float* off = (const float*)d_in[1];
    const int* shift_p = (const int*)d_in[4];
    float* out = (float*)d_out;

    const int grid = BB * CC;   // 2048 blocks, one per (b,c) plane
    defem_kernel<<<grid, 1024, 0, stream>>>(x, off, shift_p, out);
}